// Round 5
// baseline (337.762 us; speedup 1.0000x reference)
//
#include <hip/hip_runtime.h>
#include <hip/hip_bf16.h>

typedef __hip_bfloat16 bf16;
typedef __attribute__((ext_vector_type(8))) short bf16x8;
typedef __attribute__((ext_vector_type(4))) float floatx4;
typedef unsigned short ushort;

#define ROWS 32768
#define KX 96          // padded d_ext (70 -> 96)
#define XS 104         // xe LDS row stride (ushorts): 52 words % 32 = 20 -> 2-way max (free)
#define HS 520         // hid/kq LDS row stride (ushorts): 260 words % 32 = 4 -> 2-way max (free)

#define MFMA(a, b, c) __builtin_amdgcn_mfma_f32_16x16x32_bf16(a, b, c, 0, 0, 0)

__device__ __forceinline__ ushort f2bf(float f) {
  union { float f; unsigned int i; } u; u.f = f;
  return (ushort)((u.i + 0x7fffu + ((u.i >> 16) & 1u)) >> 16);   // RNE
}
__device__ __forceinline__ float b2f(ushort v) {
  union { unsigned int i; float f; } u; u.i = (unsigned int)v << 16;
  return u.f;
}

// ---------------- prep: xe (32768 x 96 bf16) + biases ----------------
__global__ void prep_misc(const float* __restrict__ x, const float* __restrict__ pos,
    const float* __restrict__ bk1, const float* __restrict__ bq1, const float* __restrict__ bv1,
    const float* __restrict__ bk2, const float* __restrict__ bq2, const float* __restrict__ bv2,
    bf16* __restrict__ xe, float* __restrict__ b1, float* __restrict__ b2)
{
  int idx = blockIdx.x * 256 + threadIdx.x;
  if (idx < ROWS * KX) {
    int r = idx / KX, col = idx - r * KX;
    float v = 0.f;
    if (col < 64)      v = x[r * 64 + col];
    else if (col < 70) v = pos[(r & 15) * 6 + (col - 64)];
    xe[idx] = __float2bfloat16(v);
  } else if (idx < ROWS * KX + 3072) {
    int i = idx - ROWS * KX;
    if (i < 1536) {
      int z = i >> 9, nl = i & 511;
      const float* s = (z == 0) ? bk1 : (z == 1) ? bq1 : bv1;
      b1[i] = s[nl];
    } else {
      int j = i - 1536;
      int z = j >> 9, nl = j & 511;
      const float* s = (z == 0) ? bk2 : (z == 1) ? bq2 : bv2;
      b2[j] = s[nl];
    }
  }
}

// ---------------- prep: tiled transpose of W1 (70x512 -> 1536x96) and W2 (512x512 -> n,k) ----------------
__global__ __launch_bounds__(256) void prep_wt(
    const float* __restrict__ Wk_h, const float* __restrict__ Wq_h, const float* __restrict__ Wv_h,
    const float* __restrict__ Wk_o, const float* __restrict__ Wq_o, const float* __restrict__ Wv_o,
    bf16* __restrict__ w1t, bf16* __restrict__ w2t)
{
  __shared__ float tile[32][33];
  const int bid = blockIdx.x;
  const int c = threadIdx.x & 31, r0 = threadIdx.x >> 5;
  if (bid < 768) {            // W2: z x nt(16) x kt(16), 32x32 tiles
    const int z = bid >> 8, rem = bid & 255;
    const int nt = rem >> 4, kt = rem & 15;
    const float* src = (z == 0) ? Wk_o : (z == 1) ? Wq_o : Wv_o;
    #pragma unroll
    for (int rr = 0; rr < 4; ++rr) {
      int r = r0 + rr * 8;
      tile[r][c] = src[(kt * 32 + r) * 512 + nt * 32 + c];
    }
    __syncthreads();
    #pragma unroll
    for (int rr = 0; rr < 4; ++rr) {
      int r = r0 + rr * 8;    // n-local
      w2t[((long)z * 512 + nt * 32 + r) * 512 + kt * 32 + c] = __float2bfloat16(tile[c][r]);
    }
  } else {                    // W1: z(3) x kt(3) x nt(16)
    const int b2i = bid - 768;
    const int z = b2i / 48, rem = b2i - z * 48;
    const int kt = rem >> 4, nt = rem & 15;
    const float* src = (z == 0) ? Wk_h : (z == 1) ? Wq_h : Wv_h;
    #pragma unroll
    for (int rr = 0; rr < 4; ++rr) {
      int r = r0 + rr * 8;
      int k = kt * 32 + r;
      tile[r][c] = (k < 70) ? src[k * 512 + nt * 32 + c] : 0.f;
    }
    __syncthreads();
    #pragma unroll
    for (int rr = 0; rr < 4; ++rr) {
      int r = r0 + rr * 8;    // n-local
      w1t[((long)z * 512 + nt * 32 + r) * KX + kt * 32 + c] = __float2bfloat16(tile[c][r]);
    }
  }
}

// ---------------- fully fused: MLPx3 + attention, one block per 32 rows (2 batches) ----------------
// 512 threads = 8 waves; wave w owns N-chunk [w*64, w*64+64) in both GEMMs.
// B-operands (weights) read directly from global (L2-resident); A from LDS; no K-loop barriers.
__global__ __launch_bounds__(512) void fused_all(
    const bf16* __restrict__ xe_g, const bf16* __restrict__ w1t,
    const bf16* __restrict__ w2t, const float* __restrict__ b1,
    const float* __restrict__ b2, const float* __restrict__ flow_mask,
    float* __restrict__ out)
{
  __shared__ ushort xe_s[32 * XS];          //  6.5 KB
  __shared__ ushort hid_s[32 * HS];         // 32.5 KB
  __shared__ ushort kq_s[2][32 * HS];       // 65 KB   [0]=k then v, [1]=q
  __shared__ ushort wn_s[2 * 4 * 16 * 40];  // 10 KB   [bat][hp][i][chl*16+j]
  __shared__ float  fm_s[16];

  const int tid  = threadIdx.x;
  const int w    = tid >> 6, lane = tid & 63;
  const int jcol = lane & 15, rgrp = lane >> 4, ko = rgrp * 8;
  const int r0   = blockIdx.x * 32;
  const int ncol0 = w * 64;

  // ---- stage xe tile (32 x 96) ----
  {
    const int row = tid >> 4, cg = tid & 15;
    if (cg < 12) {
      uint4 v = *(const uint4*)(xe_g + (long)(r0 + row) * KX + cg * 8);
      *(uint4*)&xe_s[row * XS + cg * 8] = v;
    }
  }
  if (tid < 16) fm_s[tid] = flow_mask[tid];
  __syncthreads();

  floatx4 acc[2][4];

  for (int z = 0; z < 3; ++z) {
    // ---- scores run between z=1 and z=2 (k,q complete; before v overwrites k) ----
    if (z == 2) {
      __syncthreads();   // k,q writes visible
      const int bat = w >> 2, wv4 = w & 3;
      const ushort* kb = kq_s[0] + bat * 16 * HS;
      const ushort* qb = kq_s[1] + bat * 16 * HS;
      const float fmj = fm_s[jcol];
      #pragma unroll
      for (int h = 0; h < 2; ++h) {
        const int c = wv4 + h * 4;
        floatx4 sc = {0.f, 0.f, 0.f, 0.f};
        const ushort* kr = kb + jcol * HS + c * 64 + ko;
        const ushort* qr = qb + jcol * HS + c * 64 + ko;
        bf16x8 ka0 = *(const bf16x8*)kr;
        bf16x8 ka1 = *(const bf16x8*)(kr + 32);
        bf16x8 qa0 = *(const bf16x8*)qr;
        bf16x8 qa1 = *(const bf16x8*)(qr + 32);
        sc = MFMA(ka0, qa0, sc);
        sc = MFMA(ka1, qa1, sc);
        float wv[4], ss[4];
        #pragma unroll
        for (int r = 0; r < 4; ++r) {
          const int i = rgrp * 4 + r;
          float arg = sc[r] * (fm_s[i] * fmj * 0.125f);
          float sp  = fmaxf(arg, 0.f) + log1pf(__expf(-fabsf(arg)));
          float wvv = sp + 1e-5f;
          if (i == jcol) wvv = 0.f;     // mask_self
          wv[r] = wvv; ss[r] = wvv;
        }
        #pragma unroll
        for (int m = 1; m < 16; m <<= 1) {
          #pragma unroll
          for (int r = 0; r < 4; ++r) ss[r] += __shfl_xor(ss[r], m);
        }
        const int hp = c >> 1, chl = c & 1;
        #pragma unroll
        for (int r = 0; r < 4; ++r) {
          const int i = rgrp * 4 + r;
          wn_s[bat * 2560 + hp * 640 + i * 40 + chl * 16 + jcol] = f2bf(wv[r] / ss[r] * fmj);
        }
      }
    }

    // ---- GEMM1: hid = silu(xe @ W1t_z^T + b1_z), M=32 N=512 K=96 ----
    #pragma unroll
    for (int mf = 0; mf < 2; ++mf)
      #pragma unroll
      for (int nf = 0; nf < 4; ++nf) acc[mf][nf] = (floatx4){0.f, 0.f, 0.f, 0.f};
    #pragma unroll
    for (int kk = 0; kk < 3; ++kk) {
      const int k0 = kk * 32;
      bf16x8 a0 = *(const bf16x8*)&xe_s[jcol * XS + k0 + ko];
      bf16x8 a1 = *(const bf16x8*)&xe_s[(16 + jcol) * XS + k0 + ko];
      #pragma unroll
      for (int nf = 0; nf < 4; ++nf) {
        const long n = (long)z * 512 + ncol0 + nf * 16 + jcol;
        bf16x8 bfr = *(const bf16x8*)(w1t + n * KX + k0 + ko);
        acc[0][nf] = MFMA(a0, bfr, acc[0][nf]);
        acc[1][nf] = MFMA(a1, bfr, acc[1][nf]);
      }
    }
    __syncthreads();   // all waves done reading hid (prev z) / scores' k-reads (z=2)
    #pragma unroll
    for (int mf = 0; mf < 2; ++mf)
      #pragma unroll
      for (int nf = 0; nf < 4; ++nf) {
        const int col = ncol0 + nf * 16 + jcol;
        const float bv = b1[z * 512 + col];
        #pragma unroll
        for (int r = 0; r < 4; ++r) {
          float v = acc[mf][nf][r] + bv;
          v = v / (1.f + __expf(-v));   // silu
          hid_s[(mf * 16 + rgrp * 4 + r) * HS + col] = f2bf(v);
        }
      }
    __syncthreads();   // hid visible

    // ---- GEMM2: kqv_z = hid @ W2t_z^T + b2_z, M=32 N=512 K=512 ----
    #pragma unroll
    for (int mf = 0; mf < 2; ++mf)
      #pragma unroll
      for (int nf = 0; nf < 4; ++nf) acc[mf][nf] = (floatx4){0.f, 0.f, 0.f, 0.f};
    #pragma unroll 4
    for (int kk = 0; kk < 16; ++kk) {
      const int k0 = kk * 32;
      bf16x8 a0 = *(const bf16x8*)&hid_s[jcol * HS + k0 + ko];
      bf16x8 a1 = *(const bf16x8*)&hid_s[(16 + jcol) * HS + k0 + ko];
      #pragma unroll
      for (int nf = 0; nf < 4; ++nf) {
        const long n = (long)z * 512 + ncol0 + nf * 16 + jcol;
        bf16x8 bfr = *(const bf16x8*)(w2t + n * 512 + k0 + ko);
        acc[0][nf] = MFMA(a0, bfr, acc[0][nf]);
        acc[1][nf] = MFMA(a1, bfr, acc[1][nf]);
      }
    }
    ushort* dst = (z == 1) ? kq_s[1] : kq_s[0];   // z0->k, z1->q, z2->v (overwrites k)
    #pragma unroll
    for (int mf = 0; mf < 2; ++mf)
      #pragma unroll
      for (int nf = 0; nf < 4; ++nf) {
        const int col = ncol0 + nf * 16 + jcol;
        const float bv = b2[z * 512 + col];
        #pragma unroll
        for (int r = 0; r < 4; ++r)
          dst[(mf * 16 + rgrp * 4 + r) * HS + col] = f2bf(acc[mf][nf][r] + bv);
      }
  }
  __syncthreads();   // v + wn visible

  // ---- PV: O[i, dcol] = sum_hp Wn_hp(16x32) x Vpair(32x16) ----
  {
    const int bat  = w >> 2;
    const int dcol = (w & 3) * 16 + jcol;
    floatx4 o = {0.f, 0.f, 0.f, 0.f};
    #pragma unroll
    for (int hp = 0; hp < 4; ++hp) {
      bf16x8 af = *(const bf16x8*)&wn_s[bat * 2560 + hp * 640 + jcol * 40 + ko];
      const int c  = 2 * hp + (ko >> 4);
      const int jb = ko & 15;
      bf16x8 bfr;
      #pragma unroll
      for (int e = 0; e < 8; ++e)
        bfr[e] = (short)kq_s[0][(bat * 16 + jb + e) * HS + c * 64 + dcol];
      o = MFMA(af, bfr, o);
    }
    const long gb = (long)blockIdx.x * 2 + bat;
    #pragma unroll
    for (int r = 0; r < 4; ++r)
      out[gb * 1024 + (rgrp * 4 + r) * 64 + dcol] = o[r];
  }
}

// ---------------- launch ----------------
extern "C" void kernel_launch(void* const* d_in, const int* in_sizes, int n_in,
                              void* d_out, int out_size, void* d_ws, size_t ws_size,
                              hipStream_t stream) {
  const float* x    = (const float*)d_in[0];
  const float* fmk  = (const float*)d_in[1];
  const float* Wk_h = (const float*)d_in[2];
  const float* bk_h = (const float*)d_in[3];
  const float* Wk_o = (const float*)d_in[4];
  const float* bk_o = (const float*)d_in[5];
  const float* Wq_h = (const float*)d_in[6];
  const float* bq_h = (const float*)d_in[7];
  const float* Wq_o = (const float*)d_in[8];
  const float* bq_o = (const float*)d_in[9];
  const float* Wv_h = (const float*)d_in[10];
  const float* bv_h = (const float*)d_in[11];
  const float* Wv_o = (const float*)d_in[12];
  const float* bv_o = (const float*)d_in[13];
  const float* pos  = (const float*)d_in[14];
  float* out = (float*)d_out;

  // workspace (bytes): xe 6,291,456 | w1t 294,912 | w2t 1,572,864 | b1 6,144 | b2 6,144
  char* ws = (char*)d_ws;
  bf16*  xe  = (bf16*)(ws + 0);
  bf16*  w1t = (bf16*)(ws + 6291456);
  bf16*  w2t = (bf16*)(ws + 6586368);
  float* b1  = (float*)(ws + 8159232);
  float* b2  = (float*)(ws + 8165376);
  if (ws_size < 8171520ULL) return;

  prep_misc<<<12300, 256, 0, stream>>>(x, pos, bk_h, bq_h, bv_h, bk_o, bq_o, bv_o,
                                       xe, b1, b2);
  prep_wt<<<912, 256, 0, stream>>>(Wk_h, Wq_h, Wv_h, Wk_o, Wq_o, Wv_o, w1t, w2t);
  fused_all<<<1024, 512, 0, stream>>>(xe, w1t, w2t, b1, b2, fmk, out);
}

// Round 6
// 294.004 us; speedup vs baseline: 1.1488x; 1.1488x over previous
//
#include <hip/hip_runtime.h>
#include <hip/hip_bf16.h>

typedef __hip_bfloat16 bf16;
typedef __attribute__((ext_vector_type(8))) short bf16x8;
typedef __attribute__((ext_vector_type(4))) float floatx4;
typedef unsigned short ushort;

#define ROWS 32768
#define KX 96          // padded d_ext (70 -> 96)
#define HSTR 72        // hid chunk LDS row stride (ushorts)

#define MFMA(a, b, c) __builtin_amdgcn_mfma_f32_16x16x32_bf16(a, b, c, 0, 0, 0)

__device__ __forceinline__ ushort f2bf(float f) {
  union { float f; unsigned int i; } u; u.f = f;
  return (ushort)((u.i + 0x7fffu + ((u.i >> 16) & 1u)) >> 16);   // RNE
}

// ---------------- prep: xe (32768 x 96 bf16) + biases ----------------
__global__ void prep_misc(const float* __restrict__ x, const float* __restrict__ pos,
    const float* __restrict__ bk1, const float* __restrict__ bq1, const float* __restrict__ bv1,
    const float* __restrict__ bk2, const float* __restrict__ bq2, const float* __restrict__ bv2,
    bf16* __restrict__ xe, float* __restrict__ b1, float* __restrict__ b2)
{
  int idx = blockIdx.x * 256 + threadIdx.x;
  if (idx < ROWS * KX) {
    int r = idx / KX, col = idx - r * KX;
    float v = 0.f;
    if (col < 64)      v = x[r * 64 + col];
    else if (col < 70) v = pos[(r & 15) * 6 + (col - 64)];
    xe[idx] = __float2bfloat16(v);
  } else if (idx < ROWS * KX + 3072) {
    int i = idx - ROWS * KX;
    if (i < 1536) {
      int z = i >> 9, nl = i & 511;
      const float* s = (z == 0) ? bk1 : (z == 1) ? bq1 : bv1;
      b1[i] = s[nl];
    } else {
      int j = i - 1536;
      int z = j >> 9, nl = j & 511;
      const float* s = (z == 0) ? bk2 : (z == 1) ? bq2 : bv2;
      b2[j] = s[nl];
    }
  }
}

// ---------------- prep: tiled transpose W1 (70x512 -> [z*512+n]x96), W2 (512x512 -> [z*512+n]x512) ----------------
__global__ __launch_bounds__(256) void prep_wt(
    const float* __restrict__ Wk_h, const float* __restrict__ Wq_h, const float* __restrict__ Wv_h,
    const float* __restrict__ Wk_o, const float* __restrict__ Wq_o, const float* __restrict__ Wv_o,
    bf16* __restrict__ w1t, bf16* __restrict__ w2t)
{
  __shared__ float tile[32][33];
  const int bid = blockIdx.x;
  const int c = threadIdx.x & 31, r0 = threadIdx.x >> 5;
  if (bid < 768) {            // W2: z x nt(16) x kt(16), 32x32 tiles
    const int z = bid >> 8, rem = bid & 255;
    const int nt = rem >> 4, kt = rem & 15;
    const float* src = (z == 0) ? Wk_o : (z == 1) ? Wq_o : Wv_o;
    #pragma unroll
    for (int rr = 0; rr < 4; ++rr) {
      int r = r0 + rr * 8;
      tile[r][c] = src[(kt * 32 + r) * 512 + nt * 32 + c];
    }
    __syncthreads();
    #pragma unroll
    for (int rr = 0; rr < 4; ++rr) {
      int r = r0 + rr * 8;    // n-local
      w2t[((long)z * 512 + nt * 32 + r) * 512 + kt * 32 + c] = __float2bfloat16(tile[c][r]);
    }
  } else {                    // W1: z(3) x kt(3) x nt(16)
    const int b2i = bid - 768;
    const int z = b2i / 48, rem = b2i - z * 48;
    const int kt = rem >> 4, nt = rem & 15;
    const float* src = (z == 0) ? Wk_h : (z == 1) ? Wq_h : Wv_h;
    #pragma unroll
    for (int rr = 0; rr < 4; ++rr) {
      int r = r0 + rr * 8;
      int k = kt * 32 + r;
      tile[r][c] = (k < 70) ? src[k * 512 + nt * 32 + c] : 0.f;
    }
    __syncthreads();
    #pragma unroll
    for (int rr = 0; rr < 4; ++rr) {
      int r = r0 + rr * 8;    // n-local
      w1t[((long)z * 512 + nt * 32 + r) * KX + kt * 32 + c] = __float2bfloat16(tile[c][r]);
    }
  }
}

// ---------------- fused MLP: hid never touches HBM ----------------
// grid (256, 3): 128 rows x one branch z per block. 512 threads = 8 waves.
// GEMM1 wave-split: wave w -> rows [16w,16w+16), chunk cols 64.
// GEMM2 wave-split: 2m x 4n -> wave (wm,wn) owns rows [64wm,64wm+64) x cols [128wn,128wn+128).
// hid chunk (128x64) passes through double-buffered LDS; barrier = lgkmcnt-only
// (global weight loads stay in flight across it).
__global__ __launch_bounds__(512, 2) void fused_mlp(
    const bf16* __restrict__ xe, const bf16* __restrict__ w1t,
    const bf16* __restrict__ w2t, const float* __restrict__ b1,
    const float* __restrict__ b2, bf16* __restrict__ kqv)
{
  __shared__ __align__(16) ushort hidb[2][128 * HSTR];   // 36.9 KB

  const int tid  = threadIdx.x;
  const int w    = tid >> 6, lane = tid & 63;
  const int jcol = lane & 15, rgrp = lane >> 4, ko = rgrp * 8;
  const int r0   = blockIdx.x * 128;
  const int z    = blockIdx.y;
  const int wm   = w >> 2, wn = w & 3;

  // GEMM1 A-fragments (xe rows 16w + jcol), held in registers for all chunks
  bf16x8 xa0, xa1, xa2;
  {
    const bf16* xp = xe + (long)(r0 + 16 * w + jcol) * KX + ko;
    xa0 = *(const bf16x8*)(xp);
    xa1 = *(const bf16x8*)(xp + 32);
    xa2 = *(const bf16x8*)(xp + 64);
  }

  floatx4 acc2[4][8];   // [mi][nf]
  #pragma unroll
  for (int mi = 0; mi < 4; ++mi)
    #pragma unroll
    for (int nf = 0; nf < 8; ++nf) acc2[mi][nf] = (floatx4){0.f, 0.f, 0.f, 0.f};

  const bf16*  w1p = w1t + ((long)z * 512 + jcol) * KX + ko;
  const bf16*  w2p = w2t + ((long)z * 512 + 128 * wn + jcol) * 512 + ko;
  const float* b1p = b1 + z * 512;

  for (int c = 0; c < 8; ++c) {
    // ---- prefetch B2 kk=0 fragments (in flight across GEMM1 + barrier) ----
    bf16x8 b20[8];
    #pragma unroll
    for (int nf = 0; nf < 8; ++nf)
      b20[nf] = *(const bf16x8*)(w2p + (long)nf * 16 * 512 + c * 64);

    // ---- GEMM1 chunk: hid[:, 64c..64c+64), wave rows 16w..16w+16 ----
    floatx4 acc1[4];
    #pragma unroll
    for (int nf = 0; nf < 4; ++nf) acc1[nf] = (floatx4){0.f, 0.f, 0.f, 0.f};
    #pragma unroll
    for (int nf = 0; nf < 4; ++nf) {
      const bf16* bp = w1p + (long)(64 * c + nf * 16) * KX;
      bf16x8 bf0 = *(const bf16x8*)(bp);
      bf16x8 bf1 = *(const bf16x8*)(bp + 32);
      bf16x8 bf2 = *(const bf16x8*)(bp + 64);
      acc1[nf] = MFMA(xa0, bf0, acc1[nf]);
      acc1[nf] = MFMA(xa1, bf1, acc1[nf]);
      acc1[nf] = MFMA(xa2, bf2, acc1[nf]);
    }
    // ---- silu + write hid chunk to LDS ----
    ushort* hb = hidb[c & 1];
    #pragma unroll
    for (int nf = 0; nf < 4; ++nf) {
      const float bv = b1p[64 * c + nf * 16 + jcol];
      #pragma unroll
      for (int r = 0; r < 4; ++r) {
        float v = acc1[nf][r] + bv;
        v = v / (1.f + __expf(-v));                        // silu
        hb[(16 * w + rgrp * 4 + r) * HSTR + nf * 16 + jcol] = f2bf(v);
      }
    }
    // lgkm-only drain + barrier: ds_writes visible to all waves, global loads
    // (b20 / next B2) remain in flight. Buffer reuse is 2 barriers downstream.
    asm volatile("s_waitcnt lgkmcnt(0)\n\ts_barrier" ::: "memory");

    // ---- issue B2 kk=1 loads (hidden under kk=0 MFMAs) ----
    bf16x8 b21[8];
    #pragma unroll
    for (int nf = 0; nf < 8; ++nf)
      b21[nf] = *(const bf16x8*)(w2p + (long)nf * 16 * 512 + c * 64 + 32);

    // ---- GEMM2 accumulate over this 64-wide K-chunk ----
    {
      bf16x8 a[4];
      #pragma unroll
      for (int mi = 0; mi < 4; ++mi)
        a[mi] = *(const bf16x8*)&hb[(64 * wm + mi * 16 + jcol) * HSTR + ko];
      #pragma unroll
      for (int nf = 0; nf < 8; ++nf)
        #pragma unroll
        for (int mi = 0; mi < 4; ++mi)
          acc2[mi][nf] = MFMA(a[mi], b20[nf], acc2[mi][nf]);
      #pragma unroll
      for (int mi = 0; mi < 4; ++mi)
        a[mi] = *(const bf16x8*)&hb[(64 * wm + mi * 16 + jcol) * HSTR + 32 + ko];
      #pragma unroll
      for (int nf = 0; nf < 8; ++nf)
        #pragma unroll
        for (int mi = 0; mi < 4; ++mi)
          acc2[mi][nf] = MFMA(a[mi], b21[nf], acc2[mi][nf]);
    }
  }

  // ---- epilogue: + b2, pack bf16, write kqv ----
  bf16* kz = kqv + (long)z * ROWS * 512;
  #pragma unroll
  for (int mi = 0; mi < 4; ++mi) {
    const int row = r0 + 64 * wm + mi * 16 + rgrp * 4;
    #pragma unroll
    for (int nf = 0; nf < 8; ++nf) {
      const int col = 128 * wn + nf * 16 + jcol;
      const float bv = b2[z * 512 + col];
      #pragma unroll
      for (int r = 0; r < 4; ++r)
        kz[(long)(row + r) * 512 + col] = __float2bfloat16(acc2[mi][nf][r] + bv);
    }
  }
}

// ---------------- MFMA attention (validated in R3): one 256-thread block per batch ----------------
#define ATS 520   // LDS row stride in bf16 (260 words == 4 mod 32 -> 2-way max)

__global__ __launch_bounds__(256) void attn_mfma(
    const bf16* __restrict__ kqv,
    const float* __restrict__ flow_mask,
    float* __restrict__ out)
{
  __shared__ ushort ks[16 * ATS];
  __shared__ ushort qs[16 * ATS];
  __shared__ ushort vs[16 * ATS];
  __shared__ ushort wn_s[4 * 16 * 40];
  __shared__ float  fm_s[16];

  const int tid  = threadIdx.x;
  const int lane = tid & 63;
  const int wave = tid >> 6;
  const int b    = blockIdx.x;
  const long rowbase = (long)b * 16 * 512;

  {
    const uint4* gk = (const uint4*)(kqv + rowbase);
    const uint4* gq = (const uint4*)(kqv + 16777216 + rowbase);
    const uint4* gv = (const uint4*)(kqv + 33554432 + rowbase);
    #pragma unroll
    for (int g = 0; g < 4; ++g) {
      const int gid = tid + g * 256;
      const int row = gid >> 6, colg = gid & 63;
      uint4 kv = gk[row * 64 + colg];
      uint4 qv = gq[row * 64 + colg];
      uint4 vv = gv[row * 64 + colg];
      *(uint4*)&ks[row * ATS + colg * 8] = kv;
      *(uint4*)&qs[row * ATS + colg * 8] = qv;
      *(uint4*)&vs[row * ATS + colg * 8] = vv;
    }
  }
  if (tid < 16) fm_s[tid] = flow_mask[tid];
  __syncthreads();

  const int jcol = lane & 15;
  const int rgrp = lane >> 4;
  const int ko   = rgrp * 8;

  {
    const float fmj = fm_s[jcol];
    #pragma unroll
    for (int h = 0; h < 2; ++h) {
      const int c = wave + h * 4;
      floatx4 acc = {0.f, 0.f, 0.f, 0.f};
      const ushort* kr = ks + jcol * ATS + c * 64 + ko;
      const ushort* qr = qs + jcol * ATS + c * 64 + ko;
      bf16x8 a0 = *(const bf16x8*)kr;
      bf16x8 a1 = *(const bf16x8*)(kr + 32);
      bf16x8 b0 = *(const bf16x8*)qr;
      bf16x8 b1 = *(const bf16x8*)(qr + 32);
      acc = MFMA(a0, b0, acc);
      acc = MFMA(a1, b1, acc);

      float wv[4], ss[4];
      #pragma unroll
      for (int r = 0; r < 4; ++r) {
        const int i = rgrp * 4 + r;
        float arg = acc[r] * (fm_s[i] * fmj * 0.125f);
        float sp  = fmaxf(arg, 0.f) + log1pf(__expf(-fabsf(arg)));
        float wvv = sp + 1e-5f;
        if (i == jcol) wvv = 0.f;
        wv[r] = wvv; ss[r] = wvv;
      }
      #pragma unroll
      for (int m = 1; m < 16; m <<= 1) {
        #pragma unroll
        for (int r = 0; r < 4; ++r) ss[r] += __shfl_xor(ss[r], m);
      }
      const int hp = c >> 1, chl = c & 1;
      #pragma unroll
      for (int r = 0; r < 4; ++r) {
        const int i = rgrp * 4 + r;
        wn_s[hp * 640 + i * 40 + chl * 16 + jcol] = f2bf(wv[r] / ss[r] * fmj);
      }
    }
  }
  __syncthreads();

  {
    const int dcol = wave * 16 + jcol;
    floatx4 o = {0.f, 0.f, 0.f, 0.f};
    #pragma unroll
    for (int hp = 0; hp < 4; ++hp) {
      bf16x8 af = *(const bf16x8*)&wn_s[hp * 640 + jcol * 40 + ko];
      const int c  = 2 * hp + (ko >> 4);
      const int jb = ko & 15;
      bf16x8 bfr;
      #pragma unroll
      for (int e = 0; e < 8; ++e)
        bfr[e] = (short)vs[(jb + e) * ATS + c * 64 + dcol];
      o = MFMA(af, bfr, o);
    }
    float* ob = out + (long)b * 1024 + dcol;
    #pragma unroll
    for (int r = 0; r < 4; ++r) ob[(rgrp * 4 + r) * 64] = o[r];
  }
}

// ---------------- launch ----------------
extern "C" void kernel_launch(void* const* d_in, const int* in_sizes, int n_in,
                              void* d_out, int out_size, void* d_ws, size_t ws_size,
                              hipStream_t stream) {
  const float* x    = (const float*)d_in[0];
  const float* fmk  = (const float*)d_in[1];
  const float* Wk_h = (const float*)d_in[2];
  const float* bk_h = (const float*)d_in[3];
  const float* Wk_o = (const float*)d_in[4];
  const float* bk_o = (const float*)d_in[5];
  const float* Wq_h = (const float*)d_in[6];
  const float* bq_h = (const float*)d_in[7];
  const float* Wq_o = (const float*)d_in[8];
  const float* bq_o = (const float*)d_in[9];
  const float* Wv_h = (const float*)d_in[10];
  const float* bv_h = (const float*)d_in[11];
  const float* Wv_o = (const float*)d_in[12];
  const float* bv_o = (const float*)d_in[13];
  const float* pos  = (const float*)d_in[14];
  float* out = (float*)d_out;

  // workspace layout (bytes)
  char* ws = (char*)d_ws;
  bf16*  xe  = (bf16*)(ws + 0);           //   6,291,456 (32768 x 96)
  bf16*  w1t = (bf16*)(ws + 6291456);     //     294,912 (1536 x 96)
  bf16*  w2t = (bf16*)(ws + 6586368);     //   1,572,864 (1536 x 512)
  float* b1  = (float*)(ws + 8159232);    //       6,144
  float* b2  = (float*)(ws + 8165376);    //       6,144
  bf16*  kqv = (bf16*)(ws + 8171520);     // 100,663,296 (3 x 32768 x 512)
  if (ws_size < 108834816ULL) return;

  prep_misc<<<12300, 256, 0, stream>>>(x, pos, bk_h, bq_h, bv_h, bk_o, bq_o, bv_o,
                                       xe, b1, b2);
  prep_wt<<<912, 256, 0, stream>>>(Wk_h, Wq_h, Wv_h, Wk_o, Wq_o, Wv_o, w1t, w2t);
  fused_mlp<<<dim3(256, 3), 512, 0, stream>>>(xe, w1t, w2t, b1, b2, kqv);
  attn_mfma<<<2048, 256, 0, stream>>>(kqv, fmk, out);
}

// Round 7
// 265.365 us; speedup vs baseline: 1.2728x; 1.1079x over previous
//
#include <hip/hip_runtime.h>
#include <hip/hip_bf16.h>

typedef __hip_bfloat16 bf16;
typedef __attribute__((ext_vector_type(8))) short bf16x8;
typedef __attribute__((ext_vector_type(4))) float floatx4;
typedef unsigned short ushort;
typedef unsigned int uint;

#define ROWS 32768
#define KX 96          // padded d_ext (70 -> 96)
#define XSTR 104       // xe LDS row stride (ushorts): banks 4(5j+r)%32 -> balanced
#define HST 520        // hid LDS row stride (ushorts): banks 4(j+r)%32 -> balanced

#define MFMA(a, b, c) __builtin_amdgcn_mfma_f32_16x16x32_bf16(a, b, c, 0, 0, 0)

__device__ __forceinline__ ushort f2bf(float f) {
  union { float f; unsigned int i; } u; u.f = f;
  return (ushort)((u.i + 0x7fffu + ((u.i >> 16) & 1u)) >> 16);   // RNE
}

// ---------------- prep: xe (32768 x 96 bf16) + biases ----------------
__global__ void prep_misc(const float* __restrict__ x, const float* __restrict__ pos,
    const float* __restrict__ bk1, const float* __restrict__ bq1, const float* __restrict__ bv1,
    const float* __restrict__ bk2, const float* __restrict__ bq2, const float* __restrict__ bv2,
    bf16* __restrict__ xe, float* __restrict__ b1, float* __restrict__ b2)
{
  int idx = blockIdx.x * 256 + threadIdx.x;
  if (idx < ROWS * KX) {
    int r = idx / KX, col = idx - r * KX;
    float v = 0.f;
    if (col < 64)      v = x[r * 64 + col];
    else if (col < 70) v = pos[(r & 15) * 6 + (col - 64)];
    xe[idx] = __float2bfloat16(v);
  } else if (idx < ROWS * KX + 3072) {
    int i = idx - ROWS * KX;
    if (i < 1536) {
      int z = i >> 9, nl = i & 511;
      const float* s = (z == 0) ? bk1 : (z == 1) ? bq1 : bv1;
      b1[i] = s[nl];
    } else {
      int j = i - 1536;
      int z = j >> 9, nl = j & 511;
      const float* s = (z == 0) ? bk2 : (z == 1) ? bq2 : bv2;
      b2[j] = s[nl];
    }
  }
}

// ---------------- prep: tiled transpose W1 (70x512 -> [z*512+n]x96), W2 (512x512 -> n,k) ----------------
__global__ __launch_bounds__(256) void prep_wt(
    const float* __restrict__ Wk_h, const float* __restrict__ Wq_h, const float* __restrict__ Wv_h,
    const float* __restrict__ Wk_o, const float* __restrict__ Wq_o, const float* __restrict__ Wv_o,
    bf16* __restrict__ w1t, bf16* __restrict__ w2t)
{
  __shared__ float tile[32][33];
  const int bid = blockIdx.x;
  const int c = threadIdx.x & 31, r0 = threadIdx.x >> 5;
  if (bid < 768) {            // W2: z x nt(16) x kt(16)
    const int z = bid >> 8, rem = bid & 255;
    const int nt = rem >> 4, kt = rem & 15;
    const float* src = (z == 0) ? Wk_o : (z == 1) ? Wq_o : Wv_o;
    #pragma unroll
    for (int rr = 0; rr < 4; ++rr) {
      int r = r0 + rr * 8;
      tile[r][c] = src[(kt * 32 + r) * 512 + nt * 32 + c];
    }
    __syncthreads();
    #pragma unroll
    for (int rr = 0; rr < 4; ++rr) {
      int r = r0 + rr * 8;
      w2t[((long)z * 512 + nt * 32 + r) * 512 + kt * 32 + c] = __float2bfloat16(tile[c][r]);
    }
  } else {                    // W1: z(3) x kt(3) x nt(16)
    const int b2i = bid - 768;
    const int z = b2i / 48, rem = b2i - z * 48;
    const int kt = rem >> 4, nt = rem & 15;
    const float* src = (z == 0) ? Wk_h : (z == 1) ? Wq_h : Wv_h;
    #pragma unroll
    for (int rr = 0; rr < 4; ++rr) {
      int r = r0 + rr * 8;
      int k = kt * 32 + r;
      tile[r][c] = (k < 70) ? src[k * 512 + nt * 32 + c] : 0.f;
    }
    __syncthreads();
    #pragma unroll
    for (int rr = 0; rr < 4; ++rr) {
      int r = r0 + rr * 8;
      w1t[((long)z * 512 + nt * 32 + r) * KX + kt * 32 + c] = __float2bfloat16(tile[c][r]);
    }
  }
}

// ---------------- fused MLP v2: 128 rows/block, full hid in LDS, barrier-free K-loops ----------------
// grid 256 (=1 block/CU), 512 threads = 8 waves (2m x 4n), 64x64 wave tiles, 2 N-half passes.
__global__ __launch_bounds__(512, 2) void fused_mlp2(
    const bf16* __restrict__ xe_g, const bf16* __restrict__ w1t,
    const bf16* __restrict__ w2t, const float* __restrict__ b1,
    const float* __restrict__ b2, bf16* __restrict__ kqv)
{
  __shared__ __align__(16) ushort xe_s[128 * XSTR];    //  26,624 B
  __shared__ __align__(16) ushort hid_s[128 * HST];    // 133,120 B  (total 159,744 <= 160 KiB)

  const int tid  = threadIdx.x;
  const int w    = tid >> 6, lane = tid & 63;
  const int jcol = lane & 15, rgrp = lane >> 4, ko = rgrp * 8;
  const int wm   = w >> 2, wn = w & 3;
  const int r0   = blockIdx.x * 128;

  // ---- stage xe tile (128 x 96): 1536 uint4, 3 per thread ----
  #pragma unroll
  for (int s = 0; s < 3; ++s) {
    const int idx = tid + s * 512;
    const int row = idx / 12, cg = idx % 12;
    uint4 v = *(const uint4*)(xe_g + (long)(r0 + row) * KX + cg * 8);
    *(uint4*)&xe_s[row * XSTR + cg * 8] = v;
  }
  __syncthreads();

  floatx4 acc[4][4];
  bf16x8 Bb[2][4], Ab[2][4];

  for (int z = 0; z < 3; ++z) {
    // ================= GEMM1: hid = silu(xe @ W1z^T + b1z) =================
    #pragma unroll
    for (int nh = 0; nh < 2; ++nh) {
      const bf16* w1b = w1t + ((long)z * 512 + nh * 256 + 64 * wn + jcol) * KX + ko;
      bf16x8 a1f[3][4], b1f[3][4];
      #pragma unroll
      for (int kk = 0; kk < 3; ++kk)
        #pragma unroll
        for (int q = 0; q < 4; ++q) {
          b1f[kk][q] = *(const bf16x8*)(w1b + (long)q * 16 * KX + kk * 32);
          a1f[kk][q] = *(const bf16x8*)&xe_s[(64 * wm + 16 * q + jcol) * XSTR + kk * 32 + ko];
        }
      #pragma unroll
      for (int mi = 0; mi < 4; ++mi)
        #pragma unroll
        for (int nf = 0; nf < 4; ++nf) acc[mi][nf] = (floatx4){0.f, 0.f, 0.f, 0.f};
      #pragma unroll
      for (int kk = 0; kk < 3; ++kk)
        #pragma unroll
        for (int nf = 0; nf < 4; ++nf)
          #pragma unroll
          for (int mi = 0; mi < 4; ++mi)
            acc[mi][nf] = MFMA(a1f[kk][mi], b1f[kk][nf], acc[mi][nf]);
      // silu + pack column-pairs (even lanes write u32: no word-sharing conflicts)
      #pragma unroll
      for (int mi = 0; mi < 4; ++mi)
        #pragma unroll
        for (int nf = 0; nf < 4; ++nf) {
          const int col = nh * 256 + 64 * wn + 16 * nf + jcol;
          const float bv = b1[z * 512 + col];
          #pragma unroll
          for (int r = 0; r < 4; ++r) {
            float v = acc[mi][nf][r] + bv;
            v = v / (1.f + __expf(-v));            // silu
            float vp = __shfl_xor(v, 1);
            if (!(jcol & 1)) {
              uint pk = (uint)f2bf(v) | ((uint)f2bf(vp) << 16);
              *(uint*)&hid_s[(64 * wm + 16 * mi + 4 * rgrp + r) * HST + col] = pk;
            }
          }
        }
    }

    // ---- pre-barrier: issue GEMM2 nh=0 B-prologue (stays in flight across barrier) ----
    const bf16* w2b0 = w2t + ((long)z * 512 + 64 * wn + jcol) * 512 + ko;
    #pragma unroll
    for (int q = 0; q < 4; ++q) {
      Bb[0][q] = *(const bf16x8*)(w2b0 + (long)q * 16 * 512);
      Bb[1][q] = *(const bf16x8*)(w2b0 + (long)q * 16 * 512 + 32);
    }
    // lgkm-only drain: hid ds_writes visible; global B loads NOT drained (T4)
    asm volatile("s_waitcnt lgkmcnt(0)\n\ts_barrier" ::: "memory");

    // ================= GEMM2: kqv_z = hid @ W2z^T + b2z =================
    #pragma unroll
    for (int nh = 0; nh < 2; ++nh) {
      const bf16* w2b = w2t + ((long)z * 512 + nh * 256 + 64 * wn + jcol) * 512 + ko;
      #pragma unroll
      for (int q = 0; q < 4; ++q) {
        Ab[0][q] = *(const bf16x8*)&hid_s[(64 * wm + 16 * q + jcol) * HST + ko];
        Ab[1][q] = *(const bf16x8*)&hid_s[(64 * wm + 16 * q + jcol) * HST + 32 + ko];
      }
      #pragma unroll
      for (int mi = 0; mi < 4; ++mi)
        #pragma unroll
        for (int nf = 0; nf < 4; ++nf) acc[mi][nf] = (floatx4){0.f, 0.f, 0.f, 0.f};
      #pragma unroll
      for (int kk = 0; kk < 16; ++kk) {
        const int p = kk & 1;
        #pragma unroll
        for (int nf = 0; nf < 4; ++nf)
          #pragma unroll
          for (int mi = 0; mi < 4; ++mi)
            acc[mi][nf] = MFMA(Ab[p][mi], Bb[p][nf], acc[mi][nf]);
        if (kk + 2 < 16) {
          #pragma unroll
          for (int q = 0; q < 4; ++q) {
            Bb[p][q] = *(const bf16x8*)(w2b + (long)q * 16 * 512 + (kk + 2) * 32);
            Ab[p][q] = *(const bf16x8*)&hid_s[(64 * wm + 16 * q + jcol) * HST + (kk + 2) * 32 + ko];
          }
        }
      }
      if (nh == 0) {   // preload nh=1 B kk=0,1 (hidden under epilogue stores)
        #pragma unroll
        for (int q = 0; q < 4; ++q) {
          Bb[0][q] = *(const bf16x8*)(w2b + (long)(256 + q * 16) * 512);
          Bb[1][q] = *(const bf16x8*)(w2b + (long)(256 + q * 16) * 512 + 32);
        }
      }
      // epilogue
      bf16* kz = kqv + (long)z * ROWS * 512;
      #pragma unroll
      for (int mi = 0; mi < 4; ++mi)
        #pragma unroll
        for (int nf = 0; nf < 4; ++nf) {
          const int col = nh * 256 + 64 * wn + 16 * nf + jcol;
          const float bv = b2[z * 512 + col];
          #pragma unroll
          for (int r = 0; r < 4; ++r)
            kz[(long)(r0 + 64 * wm + 16 * mi + 4 * rgrp + r) * 512 + col] =
                __float2bfloat16(acc[mi][nf][r] + bv);
        }
    }
    // hid readers done (all ds_reads consumed pre-epilogue) -> lgkm-only barrier
    if (z < 2) asm volatile("s_waitcnt lgkmcnt(0)\n\ts_barrier" ::: "memory");
  }
}

// ---------------- MFMA attention (validated R3/R5): one 256-thread block per batch ----------------
#define ATS 520

__global__ __launch_bounds__(256) void attn_mfma(
    const bf16* __restrict__ kqv,
    const float* __restrict__ flow_mask,
    float* __restrict__ out)
{
  __shared__ ushort ks[16 * ATS];
  __shared__ ushort qs[16 * ATS];
  __shared__ ushort vs[16 * ATS];
  __shared__ ushort wn_s[4 * 16 * 40];
  __shared__ float  fm_s[16];

  const int tid  = threadIdx.x;
  const int lane = tid & 63;
  const int wave = tid >> 6;
  const int b    = blockIdx.x;
  const long rowbase = (long)b * 16 * 512;

  {
    const uint4* gk = (const uint4*)(kqv + rowbase);
    const uint4* gq = (const uint4*)(kqv + 16777216 + rowbase);
    const uint4* gv = (const uint4*)(kqv + 33554432 + rowbase);
    #pragma unroll
    for (int g = 0; g < 4; ++g) {
      const int gid = tid + g * 256;
      const int row = gid >> 6, colg = gid & 63;
      uint4 kv = gk[row * 64 + colg];
      uint4 qv = gq[row * 64 + colg];
      uint4 vv = gv[row * 64 + colg];
      *(uint4*)&ks[row * ATS + colg * 8] = kv;
      *(uint4*)&qs[row * ATS + colg * 8] = qv;
      *(uint4*)&vs[row * ATS + colg * 8] = vv;
    }
  }
  if (tid < 16) fm_s[tid] = flow_mask[tid];
  __syncthreads();

  const int jcol = lane & 15;
  const int rgrp = lane >> 4;
  const int ko   = rgrp * 8;

  {
    const float fmj = fm_s[jcol];
    #pragma unroll
    for (int h = 0; h < 2; ++h) {
      const int c = wave + h * 4;
      floatx4 acc = {0.f, 0.f, 0.f, 0.f};
      const ushort* kr = ks + jcol * ATS + c * 64 + ko;
      const ushort* qr = qs + jcol * ATS + c * 64 + ko;
      bf16x8 a0 = *(const bf16x8*)kr;
      bf16x8 a1 = *(const bf16x8*)(kr + 32);
      bf16x8 b0 = *(const bf16x8*)qr;
      bf16x8 b1 = *(const bf16x8*)(qr + 32);
      acc = MFMA(a0, b0, acc);
      acc = MFMA(a1, b1, acc);

      float wv[4], ss[4];
      #pragma unroll
      for (int r = 0; r < 4; ++r) {
        const int i = rgrp * 4 + r;
        float arg = acc[r] * (fm_s[i] * fmj * 0.125f);
        float sp  = fmaxf(arg, 0.f) + log1pf(__expf(-fabsf(arg)));
        float wvv = sp + 1e-5f;
        if (i == jcol) wvv = 0.f;
        wv[r] = wvv; ss[r] = wvv;
      }
      #pragma unroll
      for (int m = 1; m < 16; m <<= 1) {
        #pragma unroll
        for (int r = 0; r < 4; ++r) ss[r] += __shfl_xor(ss[r], m);
      }
      const int hp = c >> 1, chl = c & 1;
      #pragma unroll
      for (int r = 0; r < 4; ++r) {
        const int i = rgrp * 4 + r;
        wn_s[hp * 640 + i * 40 + chl * 16 + jcol] = f2bf(wv[r] / ss[r] * fmj);
      }
    }
  }
  __syncthreads();

  {
    const int dcol = wave * 16 + jcol;
    floatx4 o = {0.f, 0.f, 0.f, 0.f};
    #pragma unroll
    for (int hp = 0; hp < 4; ++hp) {
      bf16x8 af = *(const bf16x8*)&wn_s[hp * 640 + jcol * 40 + ko];
      const int c  = 2 * hp + (ko >> 4);
      const int jb = ko & 15;
      bf16x8 bfr;
      #pragma unroll
      for (int e = 0; e < 8; ++e)
        bfr[e] = (short)vs[(jb + e) * ATS + c * 64 + dcol];
      o = MFMA(af, bfr, o);
    }
    float* ob = out + (long)b * 1024 + dcol;
    #pragma unroll
    for (int r = 0; r < 4; ++r) ob[(rgrp * 4 + r) * 64] = o[r];
  }
}

// ---------------- launch ----------------
extern "C" void kernel_launch(void* const* d_in, const int* in_sizes, int n_in,
                              void* d_out, int out_size, void* d_ws, size_t ws_size,
                              hipStream_t stream) {
  const float* x    = (const float*)d_in[0];
  const float* fmk  = (const float*)d_in[1];
  const float* Wk_h = (const float*)d_in[2];
  const float* bk_h = (const float*)d_in[3];
  const float* Wk_o = (const float*)d_in[4];
  const float* bk_o = (const float*)d_in[5];
  const float* Wq_h = (const float*)d_in[6];
  const float* bq_h = (const float*)d_in[7];
  const float* Wq_o = (const float*)d_in[8];
  const float* bq_o = (const float*)d_in[9];
  const float* Wv_h = (const float*)d_in[10];
  const float* bv_h = (const float*)d_in[11];
  const float* Wv_o = (const float*)d_in[12];
  const float* bv_o = (const float*)d_in[13];
  const float* pos  = (const float*)d_in[14];
  float* out = (float*)d_out;

  // workspace layout (bytes)
  char* ws = (char*)d_ws;
  bf16*  xe  = (bf16*)(ws + 0);           //   6,291,456 (32768 x 96)
  bf16*  w1t = (bf16*)(ws + 6291456);     //     294,912 (1536 x 96)
  bf16*  w2t = (bf16*)(ws + 6586368);     //   1,572,864 (1536 x 512)
  float* b1  = (float*)(ws + 8159232);    //       6,144
  float* b2  = (float*)(ws + 8165376);    //       6,144
  bf16*  kqv = (bf16*)(ws + 8171520);     // 100,663,296 (3 x 32768 x 512)
  if (ws_size < 108834816ULL) return;

  prep_misc<<<12300, 256, 0, stream>>>(x, pos, bk_h, bq_h, bv_h, bk_o, bq_o, bv_o,
                                       xe, b1, b2);
  prep_wt<<<912, 256, 0, stream>>>(Wk_h, Wq_h, Wv_h, Wk_o, Wq_o, Wv_o, w1t, w2t);
  fused_mlp2<<<256, 512, 0, stream>>>(xe, w1t, w2t, b1, b2, kqv);
  attn_mfma<<<2048, 256, 0, stream>>>(kqv, fmk, out);
}

// Round 8
// 244.369 us; speedup vs baseline: 1.3822x; 1.0859x over previous
//
#include <hip/hip_runtime.h>
#include <hip/hip_bf16.h>

typedef __hip_bfloat16 bf16;
typedef __attribute__((ext_vector_type(8))) short bf16x8;
typedef __attribute__((ext_vector_type(4))) float floatx4;
typedef unsigned short ushort;
typedef unsigned int uint;

#define ROWS 32768
#define KX 96          // padded d_ext (70 -> 96)

#define MFMA(a, b, c) __builtin_amdgcn_mfma_f32_16x16x32_bf16(a, b, c, 0, 0, 0)

__device__ __forceinline__ ushort f2bf(float f) {
  union { float f; unsigned int i; } u; u.f = f;
  return (ushort)((u.i + 0x7fffu + ((u.i >> 16) & 1u)) >> 16);   // RNE
}

// ---------------- prep: xe (32768 x 96 bf16) + biases ----------------
__global__ void prep_misc(const float* __restrict__ x, const float* __restrict__ pos,
    const float* __restrict__ bk1, const float* __restrict__ bq1, const float* __restrict__ bv1,
    const float* __restrict__ bk2, const float* __restrict__ bq2, const float* __restrict__ bv2,
    bf16* __restrict__ xe, float* __restrict__ b1, float* __restrict__ b2)
{
  int idx = blockIdx.x * 256 + threadIdx.x;
  if (idx < ROWS * KX) {
    int r = idx / KX, col = idx - r * KX;
    float v = 0.f;
    if (col < 64)      v = x[r * 64 + col];
    else if (col < 70) v = pos[(r & 15) * 6 + (col - 64)];
    xe[idx] = __float2bfloat16(v);
  } else if (idx < ROWS * KX + 3072) {
    int i = idx - ROWS * KX;
    if (i < 1536) {
      int z = i >> 9, nl = i & 511;
      const float* s = (z == 0) ? bk1 : (z == 1) ? bq1 : bv1;
      b1[i] = s[nl];
    } else {
      int j = i - 1536;
      int z = j >> 9, nl = j & 511;
      const float* s = (z == 0) ? bk2 : (z == 1) ? bq2 : bv2;
      b2[j] = s[nl];
    }
  }
}

// ---------------- prep: tiled transpose W1 (70x512 -> [z*512+n]x96), W2 (512x512 -> n,k) ----------------
__global__ __launch_bounds__(256) void prep_wt(
    const float* __restrict__ Wk_h, const float* __restrict__ Wq_h, const float* __restrict__ Wv_h,
    const float* __restrict__ Wk_o, const float* __restrict__ Wq_o, const float* __restrict__ Wv_o,
    bf16* __restrict__ w1t, bf16* __restrict__ w2t)
{
  __shared__ float tile[32][33];
  const int bid = blockIdx.x;
  const int c = threadIdx.x & 31, r0 = threadIdx.x >> 5;
  if (bid < 768) {            // W2: z x nt(16) x kt(16)
    const int z = bid >> 8, rem = bid & 255;
    const int nt = rem >> 4, kt = rem & 15;
    const float* src = (z == 0) ? Wk_o : (z == 1) ? Wq_o : Wv_o;
    #pragma unroll
    for (int rr = 0; rr < 4; ++rr) {
      int r = r0 + rr * 8;
      tile[r][c] = src[(kt * 32 + r) * 512 + nt * 32 + c];
    }
    __syncthreads();
    #pragma unroll
    for (int rr = 0; rr < 4; ++rr) {
      int r = r0 + rr * 8;
      w2t[((long)z * 512 + nt * 32 + r) * 512 + kt * 32 + c] = __float2bfloat16(tile[c][r]);
    }
  } else {                    // W1: z(3) x kt(3) x nt(16)
    const int b2i = bid - 768;
    const int z = b2i / 48, rem = b2i - z * 48;
    const int kt = rem >> 4, nt = rem & 15;
    const float* src = (z == 0) ? Wk_h : (z == 1) ? Wq_h : Wv_h;
    #pragma unroll
    for (int rr = 0; rr < 4; ++rr) {
      int r = r0 + rr * 8;
      int k = kt * 32 + r;
      tile[r][c] = (k < 70) ? src[k * 512 + nt * 32 + c] : 0.f;
    }
    __syncthreads();
    #pragma unroll
    for (int rr = 0; rr < 4; ++rr) {
      int r = r0 + rr * 8;
      w1t[((long)z * 512 + nt * 32 + r) * KX + kt * 32 + c] = __float2bfloat16(tile[c][r]);
    }
  }
}

// ---------------- GEMM (m97-style 128x128, validated R3) + XCD-chunked swizzle ----------------
// 1-D grid 3072 = 8 xcd * 32 m-panels * 12 n-blocks (n fastest within an XCD's chunk).
// G2==1: A column-offset z*512 (lda spans 1536); epilogue: z<2 -> kqv, z==2 -> vT packed.
template<int SILU, int G2>
__global__ __launch_bounds__(256) void mlp_gemm(
    const bf16* __restrict__ A, int lda,
    const bf16* __restrict__ Bt, int ldb,
    const float* __restrict__ bias,
    bf16* __restrict__ C, int ldc, int K)
{
  __shared__ __align__(16) bf16 As[128 * 32];
  __shared__ __align__(16) bf16 Bs[128 * 32];
  const int tid  = threadIdx.x;
  const int wave = tid >> 6, lane = tid & 63;

  const int bid = blockIdx.x;
  const int xcd = bid & 7;
  const int l   = bid >> 3;          // 0..383
  const int ml  = l / 12;            // 0..31  (m-panel within xcd)
  const int nn  = l - ml * 12;       // 0..11  (n-block, fastest)
  const int bm  = (xcd * 32 + ml) * 128;
  const int bnf = nn * 128;          // flat n in [0,1536)
  const int z   = bnf >> 9;          // branch (G2 path)

  const bf16* Ap = A + (G2 ? z * 512 : 0);
  const int wm = (wave >> 1) * 64;
  const int wn = (wave & 1) * 64;

  floatx4 acc[4][4] = {};
  const int arow = lane >> 2;
  const int acol = (lane & 3) * 8;

  for (int k0 = 0; k0 < K; k0 += 32) {
    __syncthreads();
    #pragma unroll
    for (int ch = 0; ch < 2; ++ch) {
      const int rb = wave * 32 + ch * 16;
      const bf16* ga = Ap + (long)(bm + rb + arow) * lda + k0 + acol;
      const bf16* gb = Bt + (long)(bnf + rb + arow) * ldb + k0 + acol;
      __builtin_amdgcn_global_load_lds(
          (const __attribute__((address_space(1))) unsigned int*)ga,
          (__attribute__((address_space(3))) unsigned int*)(As + rb * 32), 16, 0, 0);
      __builtin_amdgcn_global_load_lds(
          (const __attribute__((address_space(1))) unsigned int*)gb,
          (__attribute__((address_space(3))) unsigned int*)(Bs + rb * 32), 16, 0, 0);
    }
    asm volatile("s_waitcnt vmcnt(0)" ::: "memory");
    __syncthreads();

    bf16x8 af[4], bfr[4];
    #pragma unroll
    for (int mi = 0; mi < 4; ++mi)
      af[mi] = *(const bf16x8*)(As + (wm + mi * 16 + (lane & 15)) * 32 + (lane >> 4) * 8);
    #pragma unroll
    for (int ni = 0; ni < 4; ++ni)
      bfr[ni] = *(const bf16x8*)(Bs + (wn + ni * 16 + (lane & 15)) * 32 + (lane >> 4) * 8);
    #pragma unroll
    for (int mi = 0; mi < 4; ++mi)
      #pragma unroll
      for (int ni = 0; ni < 4; ++ni)
        acc[mi][ni] = MFMA(af[mi], bfr[ni], acc[mi][ni]);
  }

  if (!G2 || z < 2) {
    bf16* Cz = G2 ? (C + (long)z * ROWS * 512) : C;
    #pragma unroll
    for (int mi = 0; mi < 4; ++mi) {
      #pragma unroll
      for (int ni = 0; ni < 4; ++ni) {
        const int ncf = bnf + wn + ni * 16 + (lane & 15);
        const int nc  = G2 ? (ncf & 511) : ncf;
        const float bv = bias[ncf];
        #pragma unroll
        for (int r = 0; r < 4; ++r) {
          const long m = bm + wm + mi * 16 + (lane >> 4) * 4 + r;
          float v = acc[mi][ni][r] + bv;
          if (SILU) v = v / (1.f + __expf(-v));
          Cz[m * (long)ldc + nc] = __float2bfloat16(v);
        }
      }
    }
  } else {
    // z==2: write v TRANSPOSED per batch: vT[b][nc][j], j = m&15.
    // lane's 4 r-values are 4 consecutive j -> one packed 8B store.
    ushort* vt = (ushort*)C + (long)2 * ROWS * 512;
    #pragma unroll
    for (int mi = 0; mi < 4; ++mi) {
      const int m0 = bm + wm + mi * 16;          // multiple of 16
      const long bb = (long)(m0 >> 4) * 8192;    // batch * 512 * 16
      #pragma unroll
      for (int ni = 0; ni < 4; ++ni) {
        const int ncf = bnf + wn + ni * 16 + (lane & 15);
        const int nc  = ncf & 511;
        const float bv = bias[ncf];
        float v0 = acc[mi][ni][0] + bv, v1 = acc[mi][ni][1] + bv;
        float v2 = acc[mi][ni][2] + bv, v3 = acc[mi][ni][3] + bv;
        uint2 pk;
        pk.x = (uint)f2bf(v0) | ((uint)f2bf(v1) << 16);
        pk.y = (uint)f2bf(v2) | ((uint)f2bf(v3) << 16);
        *(uint2*)(vt + bb + (long)nc * 16 + (lane >> 4) * 4) = pk;
      }
    }
  }
}

// ---------------- attention v3: no K/Q/V staging; fragments straight from L2 ----------------
// kq: k at +0, q at +16777216 (rows (b*16+j) x 512).  vT: (2048, 512, 16) at +33554432.
__global__ __launch_bounds__(256) void attn_v3(
    const bf16* __restrict__ kqv,
    const float* __restrict__ flow_mask,
    float* __restrict__ out)
{
  __shared__ ushort wn_s[4 * 16 * 40];   // [hp][i][chl*16+j], stride 40 (2-way max)
  __shared__ float  fm_s[16];

  const int tid  = threadIdx.x;
  const int lane = tid & 63;
  const int wave = tid >> 6;
  const int bid  = blockIdx.x;
  const int b    = (bid & 7) * 256 + (bid >> 3);   // XCD-match with producer GEMM

  if (tid < 16) fm_s[tid] = flow_mask[tid];
  __syncthreads();

  const int jcol = lane & 15;
  const int rgrp = lane >> 4;
  const int ko   = rgrp * 8;

  // ---- QK^T + softplus + mask + j-normalize (fragments from global/L2) ----
  {
    const bf16* kg = kqv + ((long)b * 16 + jcol) * 512;
    const bf16* qg = kg + 16777216;
    const float fmj = fm_s[jcol];
    #pragma unroll
    for (int h = 0; h < 2; ++h) {
      const int c = wave + h * 4;
      floatx4 acc = {0.f, 0.f, 0.f, 0.f};
      bf16x8 a0 = *(const bf16x8*)(kg + c * 64 + ko);
      bf16x8 a1 = *(const bf16x8*)(kg + c * 64 + 32 + ko);
      bf16x8 b0 = *(const bf16x8*)(qg + c * 64 + ko);
      bf16x8 b1 = *(const bf16x8*)(qg + c * 64 + 32 + ko);
      acc = MFMA(a0, b0, acc);
      acc = MFMA(a1, b1, acc);

      float wv[4], ss[4];
      #pragma unroll
      for (int r = 0; r < 4; ++r) {
        const int i = rgrp * 4 + r;
        float arg = acc[r] * (fm_s[i] * fmj * 0.125f);
        float sp  = fmaxf(arg, 0.f) + log1pf(__expf(-fabsf(arg)));
        float wvv = sp + 1e-5f;
        if (i == jcol) wvv = 0.f;      // mask_self
        wv[r] = wvv; ss[r] = wvv;
      }
      #pragma unroll
      for (int m = 1; m < 16; m <<= 1) {
        #pragma unroll
        for (int r = 0; r < 4; ++r) ss[r] += __shfl_xor(ss[r], m);
      }
      const int hp = c >> 1, chl = c & 1;
      #pragma unroll
      for (int r = 0; r < 4; ++r) {
        const int i = rgrp * 4 + r;
        wn_s[hp * 640 + i * 40 + chl * 16 + jcol] = f2bf(wv[r] / ss[r] * fmj);
      }
    }
  }
  __syncthreads();

  // ---- PV: B-fragments are contiguous 16B rows of vT ----
  {
    const int dcol = wave * 16 + jcol;
    const ushort* vb = (const ushort*)kqv + (long)2 * ROWS * 512 + (long)b * 8192;
    floatx4 o = {0.f, 0.f, 0.f, 0.f};
    #pragma unroll
    for (int hp = 0; hp < 4; ++hp) {
      bf16x8 af = *(const bf16x8*)&wn_s[hp * 640 + jcol * 40 + ko];
      const int c  = 2 * hp + (ko >> 4);
      const int jb = ko & 15;
      bf16x8 bfr = *(const bf16x8*)(vb + (long)(c * 64 + dcol) * 16 + jb);
      o = MFMA(af, bfr, o);
    }
    float* ob = out + (long)b * 1024 + dcol;
    #pragma unroll
    for (int r = 0; r < 4; ++r) ob[(rgrp * 4 + r) * 64] = o[r];
  }
}

// ---------------- launch ----------------
extern "C" void kernel_launch(void* const* d_in, const int* in_sizes, int n_in,
                              void* d_out, int out_size, void* d_ws, size_t ws_size,
                              hipStream_t stream) {
  const float* x    = (const float*)d_in[0];
  const float* fmk  = (const float*)d_in[1];
  const float* Wk_h = (const float*)d_in[2];
  const float* bk_h = (const float*)d_in[3];
  const float* Wk_o = (const float*)d_in[4];
  const float* bk_o = (const float*)d_in[5];
  const float* Wq_h = (const float*)d_in[6];
  const float* bq_h = (const float*)d_in[7];
  const float* Wq_o = (const float*)d_in[8];
  const float* bq_o = (const float*)d_in[9];
  const float* Wv_h = (const float*)d_in[10];
  const float* bv_h = (const float*)d_in[11];
  const float* Wv_o = (const float*)d_in[12];
  const float* bv_o = (const float*)d_in[13];
  const float* pos  = (const float*)d_in[14];
  float* out = (float*)d_out;

  // workspace layout (bytes)
  char* ws = (char*)d_ws;
  bf16*  xe  = (bf16*)(ws + 0);           //   6,291,456 (32768 x 96)
  bf16*  w1t = (bf16*)(ws + 6291456);     //     294,912 (1536 x 96)
  bf16*  w2t = (bf16*)(ws + 6586368);     //   1,572,864 (1536 x 512)
  float* b1  = (float*)(ws + 8159232);    //       6,144
  float* b2  = (float*)(ws + 8165376);    //       6,144
  bf16*  hid = (bf16*)(ws + 8171520);     // 100,663,296 (32768 x 1536)
  bf16*  kqv = (bf16*)(ws + 108834816);   // 100,663,296 (k | q | vT)
  if (ws_size < 209498112ULL) return;

  prep_misc<<<12300, 256, 0, stream>>>(x, pos, bk_h, bq_h, bv_h, bk_o, bq_o, bv_o,
                                       xe, b1, b2);
  prep_wt<<<912, 256, 0, stream>>>(Wk_h, Wq_h, Wv_h, Wk_o, Wq_o, Wv_o, w1t, w2t);
  // GEMM1: M=32768, N=1536 (flat), K=96, silu -> hid
  mlp_gemm<1, 0><<<3072, 256, 0, stream>>>(xe, KX, w1t, KX, b1, hid, 1536, KX);
  // GEMM2: M=32768, N=1536 (3 branches), K=512 -> k, q, vT
  mlp_gemm<0, 1><<<3072, 256, 0, stream>>>(hid, 1536, w2t, 512, b2, kqv, 512, 512);
  attn_v3<<<2048, 256, 0, stream>>>(kqv, fmk, out);
}